// Round 1
// baseline (840.657 us; speedup 1.0000x reference)
//
#include <hip/hip_runtime.h>
#include <stdint.h>

// Problem dims
#define S_ 2048
#define D_ 1024
#define H_ 16
#define DEP_ 64

typedef float f32x4 __attribute__((ext_vector_type(4)));
typedef __bf16 bf16x8 __attribute__((ext_vector_type(8)));

#define MFMA16(a,b,c) __builtin_amdgcn_mfma_f32_16x16x32_bf16((a),(b),(c),0,0,0)

// Output offsets (in floats): (out, E, A, pw, attv, ba, avAp, Ep)
static constexpr size_t OFF_E    = 2097152ull;
static constexpr size_t OFF_A    = 69206016ull;
static constexpr size_t OFF_PW   = 69271552ull;
static constexpr size_t OFF_ATT  = 69271616ull;
static constexpr size_t OFF_BA   = 136380480ull;
static constexpr size_t OFF_AVAP = 136380481ull;
static constexpr size_t OFF_EP   = 136381505ull;

__device__ __forceinline__ short f2b(float f) {
  union { float f; uint32_t u; } c; c.f = f;
  uint32_t u = c.u;
  uint32_t r = (u + 0x7fffu + ((u >> 16) & 1u)) >> 16;
  return (short)(r & 0xffffu);
}
__device__ __forceinline__ float b2f(short s) {
  union { uint32_t u; float f; } c; c.u = ((uint32_t)(uint16_t)s) << 16;
  return c.f;
}

// ---------------- convert inputs f32 -> bf16 ----------------
__global__ void k_cvt_in(const float* __restrict__ q, const float* __restrict__ k,
                         const float* __restrict__ v, short* __restrict__ dst) {
  const float* src = (blockIdx.z == 0) ? q : (blockIdx.z == 1) ? k : v;
  short* d = dst + (size_t)blockIdx.z * (S_*D_);
  int i = (blockIdx.x * 256 + threadIdx.x) * 4;
  float4 f = *(const float4*)(src + i);
  short4 o;
  o.x = f2b(f.x); o.y = f2b(f.y); o.z = f2b(f.z); o.w = f2b(f.w);
  *(short4*)(d + i) = o;
}

// ---------------- convert weights f32 [K][N] -> bf16 transposed [N][K] ----------------
__global__ void k_cvt_wT(const float* __restrict__ wq, const float* __restrict__ wk,
                         const float* __restrict__ wv, const float* __restrict__ wo,
                         short* __restrict__ dst) {
  __shared__ float tile[64][65];
  const float* W = (blockIdx.z == 0) ? wq : (blockIdx.z == 1) ? wk :
                   (blockIdx.z == 2) ? wv : wo;
  short* d = dst + (size_t)blockIdx.z * (D_*D_);
  int k0 = blockIdx.x * 64, n0 = blockIdx.y * 64;
  int t = threadIdx.x;
  for (int i = 0; i < 16; ++i) {
    int e = i*256 + t, r = e >> 6, c = e & 63;
    tile[r][c] = W[(size_t)(k0+r)*D_ + n0 + c];
  }
  __syncthreads();
  for (int i = 0; i < 16; ++i) {
    int e = i*256 + t, r = e >> 6, c = e & 63;
    d[(size_t)(n0+r)*D_ + k0 + c] = f2b(tile[c][r]);
  }
}

// ---------------- 128x128 bf16 GEMM: C = X @ WT^T + bias ----------------
// mode 0: write bf16 head-major [h][s][d] (qkv proj, z selects matrix)
// mode 1: write f32 [s][n] to outf (out-proj)
__global__ __launch_bounds__(256) void k_gemm(
    const short* __restrict__ Xall, const short* __restrict__ WTall,
    const float* __restrict__ b0, const float* __restrict__ b1v,
    const float* __restrict__ b2v, short* __restrict__ dstall,
    float* __restrict__ outf, int mode) {
  __shared__ short As[128*72];
  __shared__ short Bs[128*72];
  int z = blockIdx.z;
  const short* X  = Xall + (size_t)z * (S_*D_);
  const short* WT = WTall + (size_t)z * (D_*D_);
  int m0 = blockIdx.x * 128, n0 = blockIdx.y * 128;
  int t = threadIdx.x, lane = t & 63;
  int wr = t >> 7, wc = (t >> 6) & 1;
  int rA = lane & 15, kg = lane >> 4;
  f32x4 acc[4][4] = {};
  for (int kt = 0; kt < 16; ++kt) {
#pragma unroll
    for (int i = 0; i < 4; ++i) {
      int cid = i*256 + t, row = cid >> 3, c = cid & 7;
      *(int4*)&As[row*72 + c*8] = *(const int4*)&X[(size_t)(m0+row)*D_ + kt*64 + c*8];
      *(int4*)&Bs[row*72 + c*8] = *(const int4*)&WT[(size_t)(n0+row)*D_ + kt*64 + c*8];
    }
    __syncthreads();
#pragma unroll
    for (int kk = 0; kk < 2; ++kk) {
      bf16x8 a[4], b[4];
#pragma unroll
      for (int m = 0; m < 4; ++m)
        a[m] = *(const bf16x8*)&As[(wr*64 + m*16 + rA)*72 + kk*32 + kg*8];
#pragma unroll
      for (int n = 0; n < 4; ++n)
        b[n] = *(const bf16x8*)&Bs[(wc*64 + n*16 + rA)*72 + kk*32 + kg*8];
#pragma unroll
      for (int m = 0; m < 4; ++m)
#pragma unroll
        for (int n = 0; n < 4; ++n)
          acc[m][n] = MFMA16(a[m], b[n], acc[m][n]);
    }
    __syncthreads();
  }
  const float* bias = (mode == 1) ? b0 : (z == 0 ? b0 : (z == 1 ? b1v : b2v));
#pragma unroll
  for (int m = 0; m < 4; ++m) {
#pragma unroll
    for (int n = 0; n < 4; ++n) {
      int col = n0 + wc*64 + n*16 + rA;
      float bb = bias[col];
#pragma unroll
      for (int rr = 0; rr < 4; ++rr) {
        int row = m0 + wr*64 + m*16 + kg*4 + rr;
        float val = acc[m][n][rr] + bb;
        if (mode == 0) {
          int head = col >> 6, dd = col & 63;
          dstall[(size_t)z*(S_*D_) + ((size_t)head*S_ + row)*DEP_ + dd] = f2b(val);
        } else {
          outf[(size_t)row*D_ + col] = val;
        }
      }
    }
  }
}

// ---------------- bf16 transpose [h][S][64] -> [h][64][S] (z: 0=qh,1=vh) ----------------
__global__ void k_transpose(const short* __restrict__ qh, const short* __restrict__ vh,
                            short* __restrict__ qhT, short* __restrict__ vhT) {
  __shared__ short tile[64][68];
  const short* src = blockIdx.z ? vh : qh;
  short* dst = blockIdx.z ? vhT : qhT;
  int h = blockIdx.y, s0 = blockIdx.x * 64, t = threadIdx.x;
  for (int i = 0; i < 16; ++i) {
    int e = i*256 + t, r = e >> 6, c = e & 63;
    tile[r][c] = src[((size_t)h*S_ + s0 + r)*DEP_ + c];
  }
  __syncthreads();
  for (int i = 0; i < 16; ++i) {
    int e = i*256 + t, r = e >> 6, c = e & 63;
    dst[((size_t)h*DEP_ + r)*S_ + s0 + c] = tile[c][r];
  }
}

// ---------------- metric: A0[h] = qh^T @ qh  (64x64, K=2048) ----------------
__global__ __launch_bounds__(256) void k_metric(const short* __restrict__ qhT,
                                                float* __restrict__ A0) {
  __shared__ short qt[64*72];
  int h = blockIdx.x, t = threadIdx.x, lane = t & 63;
  int wr = t >> 7, wc = (t >> 6) & 1;
  int rA = lane & 15, kg = lane >> 4;
  f32x4 acc[2][2] = {};
  for (int kt = 0; kt < 32; ++kt) {
#pragma unroll
    for (int i = 0; i < 2; ++i) {
      int cid = i*256 + t, row = cid >> 3, c = cid & 7;
      *(int4*)&qt[row*72 + c*8] = *(const int4*)&qhT[((size_t)h*DEP_ + row)*S_ + kt*64 + c*8];
    }
    __syncthreads();
#pragma unroll
    for (int kk = 0; kk < 2; ++kk) {
      bf16x8 a[2], b[2];
#pragma unroll
      for (int m = 0; m < 2; ++m)
        a[m] = *(const bf16x8*)&qt[(wr*32 + m*16 + rA)*72 + kk*32 + kg*8];
#pragma unroll
      for (int n = 0; n < 2; ++n)
        b[n] = *(const bf16x8*)&qt[(wc*32 + n*16 + rA)*72 + kk*32 + kg*8];
#pragma unroll
      for (int m = 0; m < 2; ++m)
#pragma unroll
        for (int n = 0; n < 2; ++n)
          acc[m][n] = MFMA16(a[m], b[n], acc[m][n]);
    }
    __syncthreads();
  }
#pragma unroll
  for (int m = 0; m < 2; ++m)
#pragma unroll
    for (int n = 0; n < 2; ++n)
#pragma unroll
      for (int rr = 0; rr < 4; ++rr) {
        int row = wr*32 + m*16 + kg*4 + rr, col = wc*32 + n*16 + rA;
        A0[(size_t)h*4096 + row*64 + col] = acc[m][n][rr];
      }
}

// ---------------- residual dense+LN stack + power attention vector ----------------
__global__ __launch_bounds__(1024) void k_res(
    const float* __restrict__ A0, const float* __restrict__ w1,
    const float* __restrict__ b1, const float* __restrict__ w2,
    const float* __restrict__ b2, const float* __restrict__ gg,
    const float* __restrict__ be, const float* __restrict__ pwv,
    const float* __restrict__ av, const float* __restrict__ bav,
    float* __restrict__ avApW, float* __restrict__ outB) {
  __shared__ float Af[64][68];
  __shared__ float hd[64][132];
  __shared__ float red[16][64];
  int h = blockIdx.x, t = threadIdx.x;
#pragma unroll
  for (int i = 0; i < 4; ++i) { int e = i*1024 + t; Af[e>>6][e&63] = A0[(size_t)h*4096 + e]; }
  __syncthreads();
  int r = t >> 4, quad = t & 15;
  int cl = t & 127, rb = (t >> 7) * 8;
  for (int layer = 0; layer < 2; ++layer) {
    float acc[4] = {0.f, 0.f, 0.f, 0.f};
    for (int chk = 0; chk < 8; ++chk) {
      int c = chk*128 + cl;
      float a8[8];
      float bias1 = b1[layer*1024 + c];
#pragma unroll
      for (int j = 0; j < 8; ++j) a8[j] = bias1;
      for (int d = 0; d < 64; ++d) {
        float w1v = w1[((size_t)layer*64 + d)*1024 + c];
#pragma unroll
        for (int j = 0; j < 8; ++j) a8[j] += Af[rb + j][d] * w1v;
      }
#pragma unroll
      for (int j = 0; j < 8; ++j) hd[rb + j][cl] = fmaxf(a8[j], 0.f);
      __syncthreads();
      for (int c2 = 0; c2 < 128; ++c2) {
        float hv = hd[r][c2];
        float4 w2v = *(const float4*)&w2[((size_t)layer*1024 + chk*128 + c2)*64 + quad*4];
        acc[0] += hv * w2v.x; acc[1] += hv * w2v.y;
        acc[2] += hv * w2v.z; acc[3] += hv * w2v.w;
      }
      __syncthreads();
    }
    float x[4], s1 = 0.f, s2 = 0.f;
#pragma unroll
    for (int j = 0; j < 4; ++j) {
      x[j] = acc[j] + b2[layer*64 + quad*4 + j] + Af[r][quad*4 + j];
      s1 += x[j]; s2 += x[j]*x[j];
    }
#pragma unroll
    for (int sh = 1; sh < 16; sh <<= 1) { s1 += __shfl_xor(s1, sh); s2 += __shfl_xor(s2, sh); }
    float mean = s1 * (1.f/64.f);
    float var  = s2 * (1.f/64.f) - mean*mean;
    float rstd = rsqrtf(var + 1e-6f);
    float nx[4];
#pragma unroll
    for (int j = 0; j < 4; ++j) {
      int col = quad*4 + j;
      nx[j] = (x[j] - mean)*rstd*gg[layer*64 + col] + be[layer*64 + col];
    }
    __syncthreads();
#pragma unroll
    for (int j = 0; j < 4; ++j) Af[r][quad*4 + j] = nx[j];
    __syncthreads();
  }
#pragma unroll
  for (int i = 0; i < 4; ++i) { int e = i*1024 + t; outB[OFF_A + (size_t)h*4096 + e] = Af[e>>6][e&63]; }
  {
    int e = t & 63, dg = t >> 6;
    float pe = pwv[e], p = 0.f;
#pragma unroll
    for (int j = 0; j < 4; ++j) {
      int d = dg*4 + j;
      p += av[d] * powf(fabsf(Af[d][e]) + 1e-9f, pe);
    }
    red[dg][e] = p;
  }
  __syncthreads();
  if (t < 64) {
    float tot = 0.f;
#pragma unroll
    for (int g2 = 0; g2 < 16; ++g2) tot += red[g2][t];
    avApW[h*64 + t] = tot;
    outB[OFF_AVAP + h*64 + t] = tot;
  }
  if (h == 0) {
    if (t < 64) outB[OFF_PW + t] = pwv[t];
    if (t == 0) outB[OFF_BA] = bav[0];
  }
}

// ---------------- qs = qh * avAp (bf16) ----------------
__global__ void k_scaleq(const short* __restrict__ qh, const float* __restrict__ avAp,
                         short* __restrict__ qs) {
  int i = (blockIdx.x * 256 + threadIdx.x) * 8;
  int h = i >> 17, d0 = i & 63;
  union { int4 v; short s[8]; } in, out;
  in.v = *(const int4*)(qh + i);
#pragma unroll
  for (int j = 0; j < 8; ++j) out.s[j] = f2b(b2f(in.s[j]) * avAp[h*64 + d0 + j]);
  *(int4*)(qs + i) = out.v;
}

// ---------------- pass1: E, Ep, softmax partials ----------------
__global__ __launch_bounds__(256) void k_pass1(
    const short* __restrict__ qs, const short* __restrict__ kh,
    const float* __restrict__ mask, const float* __restrict__ bap,
    float* __restrict__ outB, float2* __restrict__ part) {
  __shared__ short Qs[128*64];
  __shared__ short Ks[128*64];
  int tt = blockIdx.x, st = blockIdx.y, h = blockIdx.z;
  int s0 = st*128, t0 = tt*128;
  int t = threadIdx.x, lane = t & 63;
  int wr = t >> 7, wc = (t >> 6) & 1;
  int rA = lane & 15, kg = lane >> 4;
#pragma unroll
  for (int i = 0; i < 4; ++i) {
    int cid = i*256 + t, row = cid >> 3, c = cid & 7, cs = c ^ (row & 7);
    *(int4*)&Qs[row*64 + cs*8] = *(const int4*)&qs[((size_t)h*S_ + s0 + row)*DEP_ + c*8];
    *(int4*)&Ks[row*64 + cs*8] = *(const int4*)&kh[((size_t)h*S_ + t0 + row)*DEP_ + c*8];
  }
  __syncthreads();
  f32x4 acc[4][4] = {};
#pragma unroll
  for (int kk = 0; kk < 2; ++kk) {
    bf16x8 a[4], b[4];
#pragma unroll
    for (int m = 0; m < 4; ++m) {
      int row = wr*64 + m*16 + rA, c = (kk*4 + kg) ^ (row & 7);
      a[m] = *(const bf16x8*)&Qs[row*64 + c*8];
    }
#pragma unroll
    for (int n = 0; n < 4; ++n) {
      int row = wc*64 + n*16 + rA, c = (kk*4 + kg) ^ (row & 7);
      b[n] = *(const bf16x8*)&Ks[row*64 + c*8];
    }
#pragma unroll
    for (int m = 0; m < 4; ++m)
#pragma unroll
      for (int n = 0; n < 4; ++n)
        acc[m][n] = MFMA16(a[m], b[n], acc[m][n]);
  }
  float bav = bap[0];
  int colb = wc*64 + rA;
  float mk[4];
#pragma unroll
  for (int n = 0; n < 4; ++n) mk[n] = mask[t0 + colb + n*16] * (-1e9f);
  float* Eo  = outB + OFF_E;
  float* Epo = outB + OFF_EP;
#pragma unroll
  for (int m = 0; m < 4; ++m) {
#pragma unroll
    for (int rr = 0; rr < 4; ++rr) {
      int row = s0 + wr*64 + m*16 + kg*4 + rr;
      size_t base = ((size_t)h*S_ + row)*S_ + t0 + colb;
      float ep4[4], mx = -3.4e38f;
#pragma unroll
      for (int n = 0; n < 4; ++n) {
        float e = acc[m][n][rr];
        Eo[base + n*16] = e;
        float ep = (e > 0.f ? e : 0.2f*e) + bav + mk[n];
        Epo[base + n*16] = ep;
        ep4[n] = ep;
        mx = fmaxf(mx, ep);
      }
#pragma unroll
      for (int sh = 1; sh < 16; sh <<= 1) mx = fmaxf(mx, __shfl_xor(mx, sh));
      float sm = 0.f;
#pragma unroll
      for (int n = 0; n < 4; ++n) sm += expf(ep4[n] - mx);
#pragma unroll
      for (int sh = 1; sh < 16; sh <<= 1) sm += __shfl_xor(sm, sh);
      if (rA == 0)
        part[((size_t)(h*S_ + row)*16 + tt)*2 + wc] = make_float2(mx, sm);
    }
  }
}

// ---------------- softmax stats reduce ----------------
__global__ void k_sreduce(const float2* __restrict__ part, float2* __restrict__ fin) {
  int row = blockIdx.x * 256 + threadIdx.x;
  const float2* pp = part + (size_t)row * 32;
  float M = -3.4e38f;
  float2 p[32];
#pragma unroll
  for (int i = 0; i < 32; ++i) { p[i] = pp[i]; M = fmaxf(M, p[i].x); }
  float L = 0.f;
#pragma unroll
  for (int i = 0; i < 32; ++i) L += p[i].y * expf(p[i].x - M);
  fin[row] = make_float2(M, L);
}

// ---------------- pass2: attv + PV + Hnext ----------------
__global__ __launch_bounds__(256) void k_pass2(
    const short* __restrict__ qs, const short* __restrict__ kh,
    const short* __restrict__ vhT, const float* __restrict__ mask,
    const float* __restrict__ bap, const float2* __restrict__ fin,
    float* __restrict__ attv, short* __restrict__ Hn) {
  __shared__ short Qs[128*64];
  __shared__ short KP[128*128];   // union: kh tile (stride 64) / P tile (stride 128)
  __shared__ short Vs[64*128];
  int st = blockIdx.x, h = blockIdx.y;
  int s0 = st * 128;
  int t = threadIdx.x, lane = t & 63;
  int wr = t >> 7, wc = (t >> 6) & 1;
  int rA = lane & 15, kg = lane >> 4;
#pragma unroll
  for (int i = 0; i < 4; ++i) {
    int cid = i*256 + t, row = cid >> 3, c = cid & 7, cs = c ^ (row & 7);
    *(int4*)&Qs[row*64 + cs*8] = *(const int4*)&qs[((size_t)h*S_ + s0 + row)*DEP_ + c*8];
  }
  float Ms[4][4], Lr[4][4];
#pragma unroll
  for (int m = 0; m < 4; ++m)
#pragma unroll
    for (int rr = 0; rr < 4; ++rr) {
      int row = s0 + wr*64 + m*16 + kg*4 + rr;
      float2 f = fin[h*S_ + row];
      Ms[m][rr] = f.x;
      Lr[m][rr] = 1.f / f.y;
    }
  float bav = bap[0];
  __syncthreads();
  bf16x8 aq[4][2];
#pragma unroll
  for (int m = 0; m < 4; ++m)
#pragma unroll
    for (int kk = 0; kk < 2; ++kk) {
      int row = wr*64 + m*16 + rA, c = (kk*4 + kg) ^ (row & 7);
      aq[m][kk] = *(const bf16x8*)&Qs[row*64 + c*8];
    }
  f32x4 acc2[4][2] = {};
  for (int tt = 0; tt < 16; ++tt) {
    int t0 = tt * 128;
    __syncthreads();    // prev iteration's P/V reads done
#pragma unroll
    for (int i = 0; i < 4; ++i) {
      int cid = i*256 + t, row = cid >> 3, c = cid & 7, cs = c ^ (row & 7);
      *(int4*)&KP[row*64 + cs*8] = *(const int4*)&kh[((size_t)h*S_ + t0 + row)*DEP_ + c*8];
    }
#pragma unroll
    for (int i = 0; i < 4; ++i) {
      int cid = i*256 + t, row = cid >> 4, c = cid & 15, cs = c ^ (row & 7);
      *(int4*)&Vs[row*128 + cs*8] = *(const int4*)&vhT[((size_t)h*DEP_ + row)*S_ + t0 + c*8];
    }
    __syncthreads();
    f32x4 accE[4][4] = {};
#pragma unroll
    for (int kk = 0; kk < 2; ++kk) {
      bf16x8 b[4];
#pragma unroll
      for (int n = 0; n < 4; ++n) {
        int row = wc*64 + n*16 + rA, c = (kk*4 + kg) ^ (row & 7);
        b[n] = *(const bf16x8*)&KP[row*64 + c*8];
      }
#pragma unroll
      for (int m = 0; m < 4; ++m)
#pragma unroll
        for (int n = 0; n < 4; ++n)
          accE[m][n] = MFMA16(aq[m][kk], b[n], accE[m][n]);
    }
    int colb = wc*64 + rA;
    float mk[4];
#pragma unroll
    for (int n = 0; n < 4; ++n) mk[n] = mask[t0 + colb + n*16] * (-1e9f);
#pragma unroll
    for (int m = 0; m < 4; ++m)
#pragma unroll
      for (int rr = 0; rr < 4; ++rr) {
        int row = s0 + wr*64 + m*16 + kg*4 + rr;
        size_t base = ((size_t)h*S_ + row)*S_ + t0 + colb;
#pragma unroll
        for (int n = 0; n < 4; ++n) {
          float e = accE[m][n][rr];
          float ep = (e > 0.f ? e : 0.2f*e) + bav + mk[n];
          float p = expf(ep - Ms[m][rr]) * Lr[m][rr];
          attv[base + n*16] = p;
          accE[m][n][rr] = p;
        }
      }
    __syncthreads();    // all kh fragment reads done before P overwrites
#pragma unroll
    for (int m = 0; m < 4; ++m)
#pragma unroll
      for (int rr = 0; rr < 4; ++rr) {
        int row = wr*64 + m*16 + kg*4 + rr;
#pragma unroll
        for (int n = 0; n < 4; ++n) {
          int col = wc*64 + n*16 + rA;
          int ch = (col >> 3) ^ (row & 7);
          KP[row*128 + ch*8 + (col & 7)] = f2b(accE[m][n][rr]);
        }
      }
    __syncthreads();
#pragma unroll
    for (int kk = 0; kk < 4; ++kk) {
      bf16x8 ap[4], bv[2];
#pragma unroll
      for (int m = 0; m < 4; ++m) {
        int row = wr*64 + m*16 + rA, c = (kk*4 + kg) ^ (row & 7);
        ap[m] = *(const bf16x8*)&KP[row*128 + c*8];
      }
#pragma unroll
      for (int n = 0; n < 2; ++n) {
        int dd = wc*32 + n*16 + rA, c = (kk*4 + kg) ^ (dd & 7);
        bv[n] = *(const bf16x8*)&Vs[dd*128 + c*8];
      }
#pragma unroll
      for (int m = 0; m < 4; ++m)
#pragma unroll
        for (int n = 0; n < 2; ++n)
          acc2[m][n] = MFMA16(ap[m], bv[n], acc2[m][n]);
    }
  }
#pragma unroll
  for (int m = 0; m < 4; ++m)
#pragma unroll
    for (int n = 0; n < 2; ++n)
#pragma unroll
      for (int rr = 0; rr < 4; ++rr) {
        int row = s0 + wr*64 + m*16 + kg*4 + rr;
        int dd = wc*32 + n*16 + rA;
        Hn[(size_t)row*D_ + h*DEP_ + dd] = f2b(acc2[m][n][rr]);
      }
}

extern "C" void kernel_launch(void* const* d_in, const int* in_sizes, int n_in,
                              void* d_out, int out_size, void* d_ws, size_t ws_size,
                              hipStream_t stream) {
  (void)in_sizes; (void)n_in; (void)out_size; (void)ws_size;
  const float* q    = (const float*)d_in[0];
  const float* k    = (const float*)d_in[1];
  const float* v    = (const float*)d_in[2];
  const float* mask = (const float*)d_in[3];
  const float* wq_w = (const float*)d_in[4];
  const float* wq_b = (const float*)d_in[5];
  const float* wk_w = (const float*)d_in[6];
  const float* wk_b = (const float*)d_in[7];
  const float* wv_w = (const float*)d_in[8];
  const float* wv_b = (const float*)d_in[9];
  const float* wo_w = (const float*)d_in[10];
  const float* wo_b = (const float*)d_in[11];
  const float* rl_w1 = (const float*)d_in[12];
  const float* rl_b1 = (const float*)d_in[13];
  const float* rl_w2 = (const float*)d_in[14];
  const float* rl_b2 = (const float*)d_in[15];
  const float* rl_g  = (const float*)d_in[16];
  const float* rl_be = (const float*)d_in[17];
  const float* pw    = (const float*)d_in[18];
  const float* avec  = (const float*)d_in[19];
  const float* ba    = (const float*)d_in[20];
  float* outf = (float*)d_out;

  // Workspace map (bytes), with lifetime-based reuse; peak ~32.3 MB.
  char* w = (char*)d_ws;
  short* xbf  = (short*)(w);                          // 0..12M   (dead after proj GEMM)
  short* wT   = (short*)(w + (12u << 20));            // 12..20M  (woT @18M used at end)
  short* qh   = (short*)(w + (20u << 20));            // 20..24M
  short* kh   = (short*)(w + (24u << 20));            // 24..28M
  short* vh   = (short*)(w + (28u << 20));            // 28..32M  (dead after transpose)
  short* qhT  = (short*)(w);                          // 0..4M    (over xbf-q)
  short* vhT  = (short*)(w + (4u << 20));             // 4..8M    (over xbf-k)
  float2* part = (float2*)(w + (8u << 20));           // 8..16M   (over xbf-v + wqT/wkT)
  float2* fin  = (float2*)(w + (16u << 20));          // 16..16.25M (over wvT)
  short* qs   = (short*)(w + (28u << 20));            // over vh
  float* A0   = (float*)(w + (32u << 20));            // 256 KB
  float* avApW = (float*)(w + (32u << 20) + (1u << 18)); // 4 KB
  short* Hn   = (short*)(w + (20u << 20));            // over qh

  // 1. f32 -> bf16 inputs
  k_cvt_in<<<dim3(2048, 1, 3), 256, 0, stream>>>(q, k, v, xbf);
  // 2. transposed bf16 weights
  k_cvt_wT<<<dim3(16, 16, 4), 256, 0, stream>>>(wq_w, wk_w, wv_w, wo_w, wT);
  // 3. QKV projections -> head-major bf16 qh/kh/vh
  k_gemm<<<dim3(16, 8, 3), 256, 0, stream>>>(xbf, wT, wq_b, wk_b, wv_b, qh, nullptr, 0);
  // 4. transposes for metric (qhT) and PV (vhT)
  k_transpose<<<dim3(32, 16, 2), 256, 0, stream>>>(qh, vh, qhT, vhT);
  // 5. metric tensor A0 = qh^T qh
  k_metric<<<dim3(16), 256, 0, stream>>>(qhT, A0);
  // 6. res layers + LN + power/avAp + write A, pw, ba, avAp outputs
  k_res<<<dim3(16), 1024, 0, stream>>>(A0, rl_w1, rl_b1, rl_w2, rl_b2, rl_g, rl_be,
                                       pw, avec, ba, avApW, outf);
  // 7. qs = qh * avAp
  k_scaleq<<<dim3(1024), 256, 0, stream>>>(qh, avApW, qs);
  // 8. E / Ep + softmax partials
  k_pass1<<<dim3(16, 16, 16), 256, 0, stream>>>(qs, kh, mask, ba, outf, part);
  // 9. softmax stats
  k_sreduce<<<dim3(128), 256, 0, stream>>>(part, fin);
  // 10. attv + PV -> Hnext
  k_pass2<<<dim3(16, 16), 256, 0, stream>>>(qs, kh, vhT, mask, ba, fin,
                                            outf + OFF_ATT, Hn);
  // 11. out = Hnext @ wo + wo_b
  k_gemm<<<dim3(16, 8, 1), 256, 0, stream>>>(Hn, wT + 3u*D_*D_, wo_b, wo_b, wo_b,
                                             nullptr, outf, 1);
}

// Round 2
// 632.548 us; speedup vs baseline: 1.3290x; 1.3290x over previous
//
#include <hip/hip_runtime.h>
#include <stdint.h>

#define S_ 2048
#define D_ 1024
#define H_ 16
#define DEP_ 64

typedef float f32x4 __attribute__((ext_vector_type(4)));
typedef __bf16 bf16x8 __attribute__((ext_vector_type(8)));

#define MFMA16(a,b,c) __builtin_amdgcn_mfma_f32_16x16x32_bf16((a),(b),(c),0,0,0)

// Output offsets (floats): (out, E, A, pw, attv, ba, avAp, Ep)
static constexpr size_t OFF_E    = 2097152ull;
static constexpr size_t OFF_A    = 69206016ull;
static constexpr size_t OFF_PW   = 69271552ull;
static constexpr size_t OFF_ATT  = 69271616ull;
static constexpr size_t OFF_BA   = 136380480ull;
static constexpr size_t OFF_AVAP = 136380481ull;
static constexpr size_t OFF_EP   = 136381505ull;

__device__ __forceinline__ short f2b(float f) {
  union { float f; uint32_t u; } c; c.f = f;
  uint32_t u = c.u;
  uint32_t r = (u + 0x7fffu + ((u >> 16) & 1u)) >> 16;
  return (short)(r & 0xffffu);
}
__device__ __forceinline__ float b2f(short s) {
  union { uint32_t u; float f; } c; c.u = ((uint32_t)(uint16_t)s) << 16;
  return c.f;
}
__device__ __forceinline__ void st_nt(float* p, f32x4 v) {
  __builtin_nontemporal_store(v, (f32x4*)p);
}

// ---------------- convert inputs f32 -> bf16 ----------------
__global__ void k_cvt_in(const float* __restrict__ q, const float* __restrict__ k,
                         const float* __restrict__ v, short* __restrict__ dst) {
  const float* src = (blockIdx.z == 0) ? q : (blockIdx.z == 1) ? k : v;
  short* d = dst + (size_t)blockIdx.z * (S_*D_);
  int i = (blockIdx.x * 256 + threadIdx.x) * 4;
  float4 f = *(const float4*)(src + i);
  short4 o;
  o.x = f2b(f.x); o.y = f2b(f.y); o.z = f2b(f.z); o.w = f2b(f.w);
  *(short4*)(d + i) = o;
}

// ---------------- convert weights f32 [K][N] -> bf16 transposed [N][K] ----------------
__global__ void k_cvt_wT(const float* __restrict__ wq, const float* __restrict__ wk,
                         const float* __restrict__ wv, const float* __restrict__ wo,
                         short* __restrict__ dst) {
  __shared__ float tile[64][65];
  const float* W = (blockIdx.z == 0) ? wq : (blockIdx.z == 1) ? wk :
                   (blockIdx.z == 2) ? wv : wo;
  short* d = dst + (size_t)blockIdx.z * (D_*D_);
  int k0 = blockIdx.x * 64, n0 = blockIdx.y * 64;
  int t = threadIdx.x;
  for (int i = 0; i < 16; ++i) {
    int e = i*256 + t, r = e >> 6, c = e & 63;
    tile[r][c] = W[(size_t)(k0+r)*D_ + n0 + c];
  }
  __syncthreads();
  for (int i = 0; i < 16; ++i) {
    int e = i*256 + t, r = e >> 6, c = e & 63;
    d[(size_t)(n0+r)*D_ + k0 + c] = f2b(tile[c][r]);
  }
}

// ---------------- convert res-layer weights to bf16 (transposed for MFMA B-op) ----------------
// z = layer*2 + which; which 0: w1[64][1024]->w1T[1024][64]; which 1: w2[1024][64]->w2T[64][1024]
__global__ void k_cvt_rl(const float* __restrict__ w1, const float* __restrict__ w2,
                         short* __restrict__ w1T, short* __restrict__ w2T) {
  __shared__ float tile[64][65];
  int z = blockIdx.z, l = z >> 1, which = z & 1;
  int bx = blockIdx.x, t = threadIdx.x;
  if (which == 0) {
    const float* src = w1 + (size_t)l*65536;
    short* d = w1T + (size_t)l*65536;
    int n0 = bx*64;
    for (int i = 0; i < 16; ++i) {
      int e = i*256 + t, r = e >> 6, c = e & 63;
      tile[r][c] = src[(size_t)r*1024 + n0 + c];
    }
    __syncthreads();
    for (int i = 0; i < 16; ++i) {
      int e = i*256 + t, r = e >> 6, c = e & 63;
      d[(size_t)(n0+r)*64 + c] = f2b(tile[c][r]);
    }
  } else {
    const float* src = w2 + (size_t)l*65536;
    short* d = w2T + (size_t)l*65536;
    int k0 = bx*64;
    for (int i = 0; i < 16; ++i) {
      int e = i*256 + t, r = e >> 6, c = e & 63;
      tile[r][c] = src[(size_t)(k0+r)*64 + c];
    }
    __syncthreads();
    for (int i = 0; i < 16; ++i) {
      int e = i*256 + t, r = e >> 6, c = e & 63;
      d[(size_t)r*1024 + k0 + c] = f2b(tile[c][r]);
    }
  }
}

// ---------------- 128x128 bf16 GEMM: C = X @ WT^T + bias ----------------
__global__ __launch_bounds__(256) void k_gemm(
    const short* __restrict__ Xall, const short* __restrict__ WTall,
    const float* __restrict__ b0, const float* __restrict__ b1v,
    const float* __restrict__ b2v, short* __restrict__ dstall,
    float* __restrict__ outf, int mode) {
  __shared__ short As[128*72];
  __shared__ short Bs[128*72];
  int z = blockIdx.z;
  const short* X  = Xall + (size_t)z * (S_*D_);
  const short* WT = WTall + (size_t)z * (D_*D_);
  int m0 = blockIdx.x * 128, n0 = blockIdx.y * 128;
  int t = threadIdx.x, lane = t & 63;
  int wr = t >> 7, wc = (t >> 6) & 1;
  int rA = lane & 15, kg = lane >> 4;
  f32x4 acc[4][4] = {};
  for (int kt = 0; kt < 16; ++kt) {
#pragma unroll
    for (int i = 0; i < 4; ++i) {
      int cid = i*256 + t, row = cid >> 3, c = cid & 7;
      *(int4*)&As[row*72 + c*8] = *(const int4*)&X[(size_t)(m0+row)*D_ + kt*64 + c*8];
      *(int4*)&Bs[row*72 + c*8] = *(const int4*)&WT[(size_t)(n0+row)*D_ + kt*64 + c*8];
    }
    __syncthreads();
#pragma unroll
    for (int kk = 0; kk < 2; ++kk) {
      bf16x8 a[4], b[4];
#pragma unroll
      for (int m = 0; m < 4; ++m)
        a[m] = *(const bf16x8*)&As[(wr*64 + m*16 + rA)*72 + kk*32 + kg*8];
#pragma unroll
      for (int n = 0; n < 4; ++n)
        b[n] = *(const bf16x8*)&Bs[(wc*64 + n*16 + rA)*72 + kk*32 + kg*8];
#pragma unroll
      for (int m = 0; m < 4; ++m)
#pragma unroll
        for (int n = 0; n < 4; ++n)
          acc[m][n] = MFMA16(a[m], b[n], acc[m][n]);
    }
    __syncthreads();
  }
  const float* bias = (mode == 1) ? b0 : (z == 0 ? b0 : (z == 1 ? b1v : b2v));
#pragma unroll
  for (int m = 0; m < 4; ++m) {
#pragma unroll
    for (int n = 0; n < 4; ++n) {
      int col = n0 + wc*64 + n*16 + rA;
      float bb = bias[col];
#pragma unroll
      for (int rr = 0; rr < 4; ++rr) {
        int row = m0 + wr*64 + m*16 + kg*4 + rr;
        float val = acc[m][n][rr] + bb;
        if (mode == 0) {
          int head = col >> 6, dd = col & 63;
          dstall[(size_t)z*(S_*D_) + ((size_t)head*S_ + row)*DEP_ + dd] = f2b(val);
        } else {
          outf[(size_t)row*D_ + col] = val;
        }
      }
    }
  }
}

// ---------------- bf16 transpose [h][S][64] -> [h][64][S] ----------------
__global__ void k_transpose(const short* __restrict__ qh, const short* __restrict__ vh,
                            short* __restrict__ qhT, short* __restrict__ vhT) {
  __shared__ short tile[64][68];
  const short* src = blockIdx.z ? vh : qh;
  short* dst = blockIdx.z ? vhT : qhT;
  int h = blockIdx.y, s0 = blockIdx.x * 64, t = threadIdx.x;
  for (int i = 0; i < 16; ++i) {
    int e = i*256 + t, r = e >> 6, c = e & 63;
    tile[r][c] = src[((size_t)h*S_ + s0 + r)*DEP_ + c];
  }
  __syncthreads();
  for (int i = 0; i < 16; ++i) {
    int e = i*256 + t, r = e >> 6, c = e & 63;
    dst[((size_t)h*DEP_ + r)*S_ + s0 + c] = tile[c][r];
  }
}

// ---------------- metric: A0[h] = qh^T @ qh (f32 + bf16 outputs) ----------------
__global__ __launch_bounds__(256) void k_metric(const short* __restrict__ qhT,
                                                float* __restrict__ A0f,
                                                short* __restrict__ Afb) {
  __shared__ short qt[64*72];
  int h = blockIdx.x, t = threadIdx.x, lane = t & 63;
  int wr = t >> 7, wc = (t >> 6) & 1;
  int rA = lane & 15, kg = lane >> 4;
  f32x4 acc[2][2] = {};
  for (int kt = 0; kt < 32; ++kt) {
#pragma unroll
    for (int i = 0; i < 2; ++i) {
      int cid = i*256 + t, row = cid >> 3, c = cid & 7;
      *(int4*)&qt[row*72 + c*8] = *(const int4*)&qhT[((size_t)h*DEP_ + row)*S_ + kt*64 + c*8];
    }
    __syncthreads();
#pragma unroll
    for (int kk = 0; kk < 2; ++kk) {
      bf16x8 a[2], b[2];
#pragma unroll
      for (int m = 0; m < 2; ++m)
        a[m] = *(const bf16x8*)&qt[(wr*32 + m*16 + rA)*72 + kk*32 + kg*8];
#pragma unroll
      for (int n = 0; n < 2; ++n)
        b[n] = *(const bf16x8*)&qt[(wc*32 + n*16 + rA)*72 + kk*32 + kg*8];
#pragma unroll
      for (int m = 0; m < 2; ++m)
#pragma unroll
        for (int n = 0; n < 2; ++n)
          acc[m][n] = MFMA16(a[m], b[n], acc[m][n]);
    }
    __syncthreads();
  }
#pragma unroll
  for (int m = 0; m < 2; ++m)
#pragma unroll
    for (int n = 0; n < 2; ++n)
#pragma unroll
      for (int rr = 0; rr < 4; ++rr) {
        int row = wr*32 + m*16 + kg*4 + rr, col = wc*32 + n*16 + rA;
        float vv = acc[m][n][rr];
        A0f[(size_t)h*4096 + row*64 + col] = vv;
        Afb[(size_t)h*4096 + row*64 + col] = f2b(vv);
      }
}

// ---------------- d1: hd = relu(Af @ w1 + b1), MFMA, 64x128 tiles ----------------
__global__ __launch_bounds__(256) void k_d1(const short* __restrict__ Afb,
                                            const short* __restrict__ w1Tl,
                                            const float* __restrict__ b1l,
                                            short* __restrict__ hd) {
  __shared__ short As[64*72];
  __shared__ short Bs[128*72];
  int bcol = blockIdx.x * 128, h = blockIdx.y;
  int t = threadIdx.x, lane = t & 63, w = t >> 6;
  int rA = lane & 15, kg = lane >> 4;
#pragma unroll
  for (int i = 0; i < 2; ++i) {
    int cid = i*256 + t, row = cid >> 3, c = cid & 7;
    *(int4*)&As[row*72 + c*8] = *(const int4*)&Afb[(size_t)h*4096 + row*64 + c*8];
  }
#pragma unroll
  for (int i = 0; i < 4; ++i) {
    int cid = i*256 + t, row = cid >> 3, c = cid & 7;
    *(int4*)&Bs[row*72 + c*8] = *(const int4*)&w1Tl[(size_t)(bcol+row)*64 + c*8];
  }
  __syncthreads();
  f32x4 acc[2][4] = {};
#pragma unroll
  for (int kk = 0; kk < 2; ++kk) {
    bf16x8 aA[4], bW[2];
#pragma unroll
    for (int mf = 0; mf < 4; ++mf)
      aA[mf] = *(const bf16x8*)&As[(mf*16 + rA)*72 + kk*32 + kg*8];
#pragma unroll
    for (int nf = 0; nf < 2; ++nf)
      bW[nf] = *(const bf16x8*)&Bs[(w*32 + nf*16 + rA)*72 + kk*32 + kg*8];
#pragma unroll
    for (int nf = 0; nf < 2; ++nf)
#pragma unroll
      for (int mf = 0; mf < 4; ++mf)
        acc[nf][mf] = MFMA16(bW[nf], aA[mf], acc[nf][mf]);   // swapped: D[c][r]
  }
#pragma unroll
  for (int nf = 0; nf < 2; ++nf) {
    int cb = bcol + w*32 + nf*16 + kg*4;
    f32x4 b1v = *(const f32x4*)&b1l[cb];
#pragma unroll
    for (int mf = 0; mf < 4; ++mf) {
      int r = mf*16 + rA;
      union { int2 v; short s[4]; } pk;
#pragma unroll
      for (int rr = 0; rr < 4; ++rr)
        pk.s[rr] = f2b(fmaxf(acc[nf][mf][rr] + b1v[rr], 0.f));
      *(int2*)&hd[((size_t)h*64 + r)*1024 + cb] = pk.v;
    }
  }
}

// ---------------- d2 + LN (+ avAp on last layer) ----------------
__global__ __launch_bounds__(256) void k_d2ln(
    const short* __restrict__ hd, const short* __restrict__ w2Tl,
    const float* __restrict__ b2l, const float* __restrict__ AresIn,
    const float* __restrict__ gl, const float* __restrict__ bel,
    short* __restrict__ Afb, float* __restrict__ AresOut,
    float* __restrict__ outB, const float* __restrict__ pwv,
    const float* __restrict__ av, const float* __restrict__ bav,
    float* __restrict__ avApW, int layer) {
  __shared__ short hs[64*72];
  __shared__ short ws2[64*72];
  __shared__ float Xf[64][68];
  __shared__ float red[4][64];
  int h = blockIdx.x, t = threadIdx.x, lane = t & 63;
  int wr = t >> 7, wc = (t >> 6) & 1;
  int rA = lane & 15, kg = lane >> 4;
  f32x4 acc[2][2] = {};
  for (int kt = 0; kt < 16; ++kt) {
#pragma unroll
    for (int i = 0; i < 2; ++i) {
      int cid = i*256 + t, row = cid >> 3, c = cid & 7;
      *(int4*)&hs[row*72 + c*8]  = *(const int4*)&hd[((size_t)h*64 + row)*1024 + kt*64 + c*8];
      *(int4*)&ws2[row*72 + c*8] = *(const int4*)&w2Tl[(size_t)row*1024 + kt*64 + c*8];
    }
    __syncthreads();
#pragma unroll
    for (int kk = 0; kk < 2; ++kk) {
      bf16x8 a[2], b[2];
#pragma unroll
      for (int m = 0; m < 2; ++m)
        a[m] = *(const bf16x8*)&hs[(wr*32 + m*16 + rA)*72 + kk*32 + kg*8];
#pragma unroll
      for (int n = 0; n < 2; ++n)
        b[n] = *(const bf16x8*)&ws2[(wc*32 + n*16 + rA)*72 + kk*32 + kg*8];
#pragma unroll
      for (int m = 0; m < 2; ++m)
#pragma unroll
        for (int n = 0; n < 2; ++n)
          acc[m][n] = MFMA16(a[m], b[n], acc[m][n]);
    }
    __syncthreads();
  }
#pragma unroll
  for (int m = 0; m < 2; ++m)
#pragma unroll
    for (int n = 0; n < 2; ++n) {
      int col = wc*32 + n*16 + rA;
      float bb = b2l[col];
#pragma unroll
      for (int rr = 0; rr < 4; ++rr) {
        int row = wr*32 + m*16 + kg*4 + rr;
        Xf[row][col] = acc[m][n][rr] + bb + AresIn[(size_t)h*4096 + row*64 + col];
      }
    }
  __syncthreads();
  // LN per row (thread r=t>>2 handles 16 cols)
  int r = t >> 2, q4 = t & 3;
  float xv[16], s1 = 0.f, s2 = 0.f;
#pragma unroll
  for (int j = 0; j < 16; ++j) {
    xv[j] = Xf[r][q4*16 + j];
    s1 += xv[j]; s2 += xv[j]*xv[j];
  }
  s1 += __shfl_xor(s1, 1); s1 += __shfl_xor(s1, 2);
  s2 += __shfl_xor(s2, 1); s2 += __shfl_xor(s2, 2);
  float mean = s1 * (1.f/64.f);
  float var  = s2 * (1.f/64.f) - mean*mean;
  float rstd = rsqrtf(var + 1e-6f);
  float nx[16];
#pragma unroll
  for (int j = 0; j < 16; ++j) {
    int c = q4*16 + j;
    nx[j] = (xv[j] - mean)*rstd*gl[c] + bel[c];
    Afb[(size_t)h*4096 + r*64 + c] = f2b(nx[j]);
    if (layer == 0) AresOut[(size_t)h*4096 + r*64 + c] = nx[j];
    else            outB[OFF_A + (size_t)h*4096 + r*64 + c] = nx[j];
  }
  if (layer == 1) {
    __syncthreads();
#pragma unroll
    for (int j = 0; j < 16; ++j) Xf[r][q4*16 + j] = nx[j];
    __syncthreads();
    int e = t & 63, dg = t >> 6;
    float pe = pwv[e], p = 0.f;
    for (int j = 0; j < 16; ++j) {
      int d = dg*16 + j;
      p += av[d] * powf(fabsf(Xf[d][e]) + 1e-9f, pe);
    }
    red[dg][e] = p;
    __syncthreads();
    if (t < 64) {
      float tot = red[0][t] + red[1][t] + red[2][t] + red[3][t];
      avApW[h*64 + t] = tot;
      outB[OFF_AVAP + h*64 + t] = tot;
    }
    if (h == 0) {
      if (t < 64) outB[OFF_PW + t] = pwv[t];
      if (t == 0) outB[OFF_BA] = bav[0];
    }
  }
}

// ---------------- pass1: E, Ep (float4 nt stores), softmax partials ----------------
__global__ __launch_bounds__(256) void k_pass1(
    const short* __restrict__ qh, const short* __restrict__ kh,
    const float* __restrict__ avAp, const float* __restrict__ mask,
    const float* __restrict__ bap, float* __restrict__ outB,
    float2* __restrict__ part) {
  __shared__ short Qs[128*64];
  __shared__ short Ks[128*64];
  __shared__ float avl[64];
  int tt = blockIdx.x, st = blockIdx.y, h = blockIdx.z;
  int s0 = st*128, t0 = tt*128;
  int t = threadIdx.x, lane = t & 63;
  int wr = t >> 7, wc = (t >> 6) & 1;
  int rA = lane & 15, kg = lane >> 4;
  if (t < 16) *(f32x4*)&avl[t*4] = *(const f32x4*)&avAp[h*64 + t*4];
  __syncthreads();
#pragma unroll
  for (int i = 0; i < 4; ++i) {
    int cid = i*256 + t, row = cid >> 3, c = cid & 7, cs = c ^ (row & 7);
    union { int4 v; short s[8]; } qa, qo;
    qa.v = *(const int4*)&qh[((size_t)h*S_ + s0 + row)*DEP_ + c*8];
#pragma unroll
    for (int j = 0; j < 8; ++j) qo.s[j] = f2b(b2f(qa.s[j]) * avl[c*8 + j]);
    *(int4*)&Qs[row*64 + cs*8] = qo.v;
    *(int4*)&Ks[row*64 + cs*8] = *(const int4*)&kh[((size_t)h*S_ + t0 + row)*DEP_ + c*8];
  }
  __syncthreads();
  f32x4 acc[4][4] = {};
#pragma unroll
  for (int kk = 0; kk < 2; ++kk) {
    bf16x8 a[4], b[4];
#pragma unroll
    for (int m = 0; m < 4; ++m) {
      int row = wr*64 + m*16 + rA, c = (kk*4 + kg) ^ (row & 7);
      a[m] = *(const bf16x8*)&Qs[row*64 + c*8];
    }
#pragma unroll
    for (int n = 0; n < 4; ++n) {
      int row = wc*64 + n*16 + rA, c = (kk*4 + kg) ^ (row & 7);
      b[n] = *(const bf16x8*)&Ks[row*64 + c*8];
    }
#pragma unroll
    for (int m = 0; m < 4; ++m)
#pragma unroll
      for (int n = 0; n < 4; ++n)
        acc[m][n] = MFMA16(b[n], a[m], acc[m][n]);   // swapped: lane holds 4 consecutive t
  }
  float bav = bap[0];
  f32x4 mk[4];
#pragma unroll
  for (int n = 0; n < 4; ++n) {
    f32x4 mm = *(const f32x4*)&mask[t0 + wc*64 + n*16 + kg*4];
#pragma unroll
    for (int j = 0; j < 4; ++j) mk[n][j] = mm[j] * (-1e9f);
  }
  float* Eo  = outB + OFF_E;
  float* Epo = outB + OFF_EP;
#pragma unroll
  for (int m = 0; m < 4; ++m) {
    int row = s0 + wr*64 + m*16 + rA;
    size_t rb = ((size_t)h*S_ + row)*S_ + t0 + wc*64;
    float mx = -3.4e38f;
    f32x4 ep4[4];
#pragma unroll
    for (int n = 0; n < 4; ++n) {
      f32x4 e = acc[m][n];
      st_nt(&Eo[rb + n*16 + kg*4], e);
      f32x4 ep;
#pragma unroll
      for (int j = 0; j < 4; ++j) {
        float ee = e[j];
        ep[j] = (ee > 0.f ? ee : 0.2f*ee) + bav + mk[n][j];
        mx = fmaxf(mx, ep[j]);
      }
      ep4[n] = ep;
      st_nt(&Epo[rb + n*16 + kg*4], ep);
    }
    mx = fmaxf(mx, __shfl_xor(mx, 16));
    mx = fmaxf(mx, __shfl_xor(mx, 32));
    float sm = 0.f;
#pragma unroll
    for (int n = 0; n < 4; ++n)
#pragma unroll
      for (int j = 0; j < 4; ++j) sm += expf(ep4[n][j] - mx);
    sm += __shfl_xor(sm, 16);
    sm += __shfl_xor(sm, 32);
    if (kg == 0)
      part[((size_t)(h*S_ + row)*16 + tt)*2 + wc] = make_float2(mx, sm);
  }
}

// ---------------- softmax stats reduce ----------------
__global__ void k_sreduce(const float2* __restrict__ part, float2* __restrict__ fin) {
  int row = blockIdx.x * 256 + threadIdx.x;
  const float2* pp = part + (size_t)row * 32;
  float M = -3.4e38f;
  float2 p[32];
#pragma unroll
  for (int i = 0; i < 32; ++i) { p[i] = pp[i]; M = fmaxf(M, p[i].x); }
  float L = 0.f;
#pragma unroll
  for (int i = 0; i < 32; ++i) L += p[i].y * expf(p[i].x - M);
  fin[row] = make_float2(M, L);
}

// ---------------- pass2: attv (float4 nt) + PV + Hnext ----------------
__global__ __launch_bounds__(256) void k_pass2(
    const short* __restrict__ qh, const short* __restrict__ kh,
    const short* __restrict__ vhT, const float* __restrict__ avAp,
    const float* __restrict__ mask, const float* __restrict__ bap,
    const float2* __restrict__ fin, float* __restrict__ attv,
    short* __restrict__ Hn) {
  __shared__ short Qs[128*64];
  __shared__ short KP[128*128];   // union: kh tile (stride 64) / P tile (stride 128, swz)
  __shared__ short Vs[64*128];
  __shared__ float avl[64];
  int st = blockIdx.x, h = blockIdx.y;
  int s0 = st * 128;
  int t = threadIdx.x, lane = t & 63;
  int wr = t >> 7, wc = (t >> 6) & 1;
  int rA = lane & 15, kg = lane >> 4;
  if (t < 16) *(f32x4*)&avl[t*4] = *(const f32x4*)&avAp[h*64 + t*4];
  __syncthreads();
#pragma unroll
  for (int i = 0; i < 4; ++i) {
    int cid = i*256 + t, row = cid >> 3, c = cid & 7, cs = c ^ (row & 7);
    union { int4 v; short s[8]; } qa, qo;
    qa.v = *(const int4*)&qh[((size_t)h*S_ + s0 + row)*DEP_ + c*8];
#pragma unroll
    for (int j = 0; j < 8; ++j) qo.s[j] = f2b(b2f(qa.s[j]) * avl[c*8 + j]);
    *(int4*)&Qs[row*64 + cs*8] = qo.v;
  }
  float Ms[4], Li[4];
#pragma unroll
  for (int m = 0; m < 4; ++m) {
    float2 f = fin[h*S_ + s0 + wr*64 + m*16 + rA];
    Ms[m] = f.x; Li[m] = 1.f / f.y;
  }
  float bav = bap[0];
  __syncthreads();
  bf16x8 aq[4][2];
#pragma unroll
  for (int m = 0; m < 4; ++m)
#pragma unroll
    for (int kk = 0; kk < 2; ++kk) {
      int row = wr*64 + m*16 + rA, c = (kk*4 + kg) ^ (row & 7);
      aq[m][kk] = *(const bf16x8*)&Qs[row*64 + c*8];
    }
  f32x4 acc2[4][2] = {};
  for (int tt = 0; tt < 16; ++tt) {
    int t0 = tt * 128;
    __syncthreads();    // prev iteration's P/V reads done
#pragma unroll
    for (int i = 0; i < 4; ++i) {
      int cid = i*256 + t, row = cid >> 3, c = cid & 7, cs = c ^ (row & 7);
      *(int4*)&KP[row*64 + cs*8] = *(const int4*)&kh[((size_t)h*S_ + t0 + row)*DEP_ + c*8];
    }
#pragma unroll
    for (int i = 0; i < 4; ++i) {
      int cid = i*256 + t, row = cid >> 4, c = cid & 15, cs = c ^ (row & 7);
      *(int4*)&Vs[row*128 + cs*8] = *(const int4*)&vhT[((size_t)h*DEP_ + row)*S_ + t0 + c*8];
    }
    __syncthreads();
    f32x4 accE[4][4] = {};
#pragma unroll
    for (int kk = 0; kk < 2; ++kk) {
      bf16x8 b[4];
#pragma unroll
      for (int n = 0; n < 4; ++n) {
        int row = wc*64 + n*16 + rA, c = (kk*4 + kg) ^ (row & 7);
        b[n] = *(const bf16x8*)&KP[row*64 + c*8];
      }
#pragma unroll
      for (int m = 0; m < 4; ++m)
#pragma unroll
        for (int n = 0; n < 4; ++n)
          accE[m][n] = MFMA16(b[n], aq[m][kk], accE[m][n]);   // swapped
    }
    f32x4 mk[4];
#pragma unroll
    for (int n = 0; n < 4; ++n) {
      f32x4 mm = *(const f32x4*)&mask[t0 + wc*64 + n*16 + kg*4];
#pragma unroll
      for (int j = 0; j < 4; ++j) mk[n][j] = mm[j] * (-1e9f);
    }
#pragma unroll
    for (int m = 0; m < 4; ++m) {
      size_t rb = ((size_t)h*S_ + s0 + wr*64 + m*16 + rA)*S_ + t0 + wc*64;
#pragma unroll
      for (int n = 0; n < 4; ++n) {
        f32x4 e = accE[m][n], p;
#pragma unroll
        for (int j = 0; j < 4; ++j) {
          float ep = (e[j] > 0.f ? e[j] : 0.2f*e[j]) + bav + mk[n][j];
          p[j] = expf(ep - Ms[m]) * Li[m];
        }
        st_nt(&attv[rb + n*16 + kg*4], p);
        accE[m][n] = p;
      }
    }
    __syncthreads();    // all KP(kh) fragment reads done before P overwrites
#pragma unroll
    for (int m = 0; m < 4; ++m) {
      int srow = wr*64 + m*16 + rA;
#pragma unroll
      for (int n = 0; n < 4; ++n) {
        int tcol = wc*64 + n*16 + kg*4;
        union { int2 v; short s[4]; } pk;
#pragma unroll
        for (int j = 0; j < 4; ++j) pk.s[j] = f2b(accE[m][n][j]);
        *(int2*)((char*)KP + srow*256 + ((tcol*2) ^ ((srow & 7) << 4))) = pk.v;
      }
    }
    __syncthreads();
#pragma unroll
    for (int kkp = 0; kkp < 4; ++kkp) {
      bf16x8 ap[4], bv[2];
#pragma unroll
      for (int m = 0; m < 4; ++m) {
        int row = wr*64 + m*16 + rA;
        ap[m] = *(const bf16x8*)((const char*)KP + row*256 + ((kkp*64 + kg*16) ^ ((row & 7) << 4)));
      }
#pragma unroll
      for (int n = 0; n < 2; ++n) {
        int dd = wc*32 + n*16 + rA, c = (kkp*4 + kg) ^ (dd & 7);
        bv[n] = *(const bf16x8*)&Vs[dd*128 + c*8];
      }
#pragma unroll
      for (int m = 0; m < 4; ++m)
#pragma unroll
        for (int n = 0; n < 2; ++n)
          acc2[m][n] = MFMA16(ap[m], bv[n], acc2[m][n]);
    }
  }
#pragma unroll
  for (int m = 0; m < 4; ++m)
#pragma unroll
    for (int n = 0; n < 2; ++n)
#pragma unroll
      for (int rr = 0; rr < 4; ++rr) {
        int row = s0 + wr*64 + m*16 + kg*4 + rr;
        int dd = wc*32 + n*16 + rA;
        Hn[(size_t)row*D_ + h*DEP_ + dd] = f2b(acc2[m][n][rr]);
      }
}

extern "C" void kernel_launch(void* const* d_in, const int* in_sizes, int n_in,
                              void* d_out, int out_size, void* d_ws, size_t ws_size,
                              hipStream_t stream) {
  (void)in_sizes; (void)n_in; (void)out_size; (void)ws_size;
  const float* q    = (const float*)d_in[0];
  const float* k    = (const float*)d_in[1];
  const float* v    = (const float*)d_in[2];
  const float* mask = (const float*)d_in[3];
  const float* wq_w = (const float*)d_in[4];
  const float* wq_b = (const float*)d_in[5];
  const float* wk_w = (const float*)d_in[6];
  const float* wk_b = (const float*)d_in[7];
  const float* wv_w = (const float*)d_in[8];
  const float* wv_b = (const float*)d_in[9];
  const float* wo_w = (const float*)d_in[10];
  const float* wo_b = (const float*)d_in[11];
  const float* rl_w1 = (const float*)d_in[12];
  const float* rl_b1 = (const float*)d_in[13];
  const float* rl_w2 = (const float*)d_in[14];
  const float* rl_b2 = (const float*)d_in[15];
  const float* rl_g  = (const float*)d_in[16];
  const float* rl_be = (const float*)d_in[17];
  const float* pw    = (const float*)d_in[18];
  const float* avec  = (const float*)d_in[19];
  const float* ba    = (const float*)d_in[20];
  float* outf = (float*)d_out;

  // Workspace map (lifetime-based reuse, peak <= 32 MB)
  char* w = (char*)d_ws;
  short* xbf  = (short*)(w);                              // 0..12M (dead after QKV gemm)
  short* wT   = (short*)(w + (12u << 20));                // 12..20M (woT @18M lives to end)
  short* qh   = (short*)(w + (20u << 20));                // 20..24M
  short* kh   = (short*)(w + (24u << 20));                // 24..28M
  short* vh   = (short*)(w + (28u << 20));                // 28..32M (dead after transpose)
  short* qhT  = (short*)(w);                              // 0..4M  (over xbf-q)
  short* vhT  = (short*)(w + (4u << 20));                 // 4..8M  (over xbf-k)
  short* hd   = (short*)(w + (8u << 20));                 // 8..10M (over xbf-v)
  short* w1T  = (short*)(w + (10u << 20));                // 256KB
  short* w2T  = (short*)(w + (10u << 20) + (256u << 10)); // 256KB
  short* Afbf = (short*)(w + (10u << 20) + (512u << 10)); // 128KB
  float* Ares0 = (float*)(w + (11u << 20));               // 256KB
  float* Ares1 = (float*)(w + (11u << 20) + (256u << 10));// 256KB
  float2* part = (float2*)(w + (8u << 20));               // 8..16M (pass1 phase; res bufs dead)
  float2* fin  = (float2*)(w + (16u << 20));              // 256KB (over wvT, dead)
  float* avApW = (float*)(w + (16u << 20) + (512u << 10));// 4KB
  short* Hn   = (short*)(w + (28u << 20));                // over vh

  k_cvt_in<<<dim3(2048, 1, 3), 256, 0, stream>>>(q, k, v, xbf);
  k_cvt_wT<<<dim3(16, 16, 4), 256, 0, stream>>>(wq_w, wk_w, wv_w, wo_w, wT);
  k_gemm<<<dim3(16, 8, 3), 256, 0, stream>>>(xbf, wT, wq_b, wk_b, wv_b, qh, nullptr, 0);
  k_transpose<<<dim3(32, 16, 2), 256, 0, stream>>>(qh, vh, qhT, vhT);
  k_cvt_rl<<<dim3(16, 1, 4), 256, 0, stream>>>(rl_w1, rl_w2, w1T, w2T);
  k_metric<<<dim3(16), 256, 0, stream>>>(qhT, Ares0, Afbf);
  // res layer 0
  k_d1<<<dim3(8, 16), 256, 0, stream>>>(Afbf, w1T, rl_b1, hd);
  k_d2ln<<<dim3(16), 256, 0, stream>>>(hd, w2T, rl_b2, Ares0, rl_g, rl_be,
                                       Afbf, Ares1, outf, pw, avec, ba, avApW, 0);
  // res layer 1
  k_d1<<<dim3(8, 16), 256, 0, stream>>>(Afbf, w1T + 65536, rl_b1 + 1024, hd);
  k_d2ln<<<dim3(16), 256, 0, stream>>>(hd, w2T + 65536, rl_b2 + 64, Ares1,
                                       rl_g + 64, rl_be + 64,
                                       Afbf, Ares1, outf, pw, avec, ba, avApW, 1);
  k_pass1<<<dim3(16, 16, 16), 256, 0, stream>>>(qh, kh, avApW, mask, ba, outf, part);
  k_sreduce<<<dim3(128), 256, 0, stream>>>(part, fin);
  k_pass2<<<dim3(16, 16), 256, 0, stream>>>(qh, kh, vhT, avApW, mask, ba, fin,
                                            outf + OFF_ATT, Hn);
  k_gemm<<<dim3(16, 8, 1), 256, 0, stream>>>(Hn, wT + 3u*D_*D_, wo_b, wo_b, wo_b,
                                             nullptr, outf, 1);
}

// Round 3
// 599.452 us; speedup vs baseline: 1.4024x; 1.0552x over previous
//
#include <hip/hip_runtime.h>
#include <stdint.h>

#define S_ 2048
#define D_ 1024
#define H_ 16
#define DEP_ 64

typedef float f32x4 __attribute__((ext_vector_type(4)));
typedef __bf16 bf16x8 __attribute__((ext_vector_type(8)));

#define MFMA16(a,b,c) __builtin_amdgcn_mfma_f32_16x16x32_bf16((a),(b),(c),0,0,0)

// Output offsets (floats): (out, E, A, pw, attv, ba, avAp, Ep)
static constexpr size_t OFF_E    = 2097152ull;
static constexpr size_t OFF_A    = 69206016ull;
static constexpr size_t OFF_PW   = 69271552ull;
static constexpr size_t OFF_ATT  = 69271616ull;
static constexpr size_t OFF_BA   = 136380480ull;
static constexpr size_t OFF_AVAP = 136380481ull;
static constexpr size_t OFF_EP   = 136381505ull;

__device__ __forceinline__ short f2b(float f) {
  union { float f; uint32_t u; } c; c.f = f;
  uint32_t u = c.u;
  uint32_t r = (u + 0x7fffu + ((u >> 16) & 1u)) >> 16;
  return (short)(r & 0xffffu);
}
__device__ __forceinline__ float b2f(short s) {
  union { uint32_t u; float f; } c; c.u = ((uint32_t)(uint16_t)s) << 16;
  return c.f;
}
__device__ __forceinline__ void st_nt(float* p, f32x4 v) {
  __builtin_nontemporal_store(v, (f32x4*)p);
}

// ---------------- convert inputs f32 -> bf16 ----------------
__global__ void k_cvt_in(const float* __restrict__ q, const float* __restrict__ k,
                         const float* __restrict__ v, short* __restrict__ dst) {
  const float* src = (blockIdx.z == 0) ? q : (blockIdx.z == 1) ? k : v;
  short* d = dst + (size_t)blockIdx.z * (S_*D_);
  int i = (blockIdx.x * 256 + threadIdx.x) * 4;
  float4 f = *(const float4*)(src + i);
  short4 o;
  o.x = f2b(f.x); o.y = f2b(f.y); o.z = f2b(f.z); o.w = f2b(f.w);
  *(short4*)(d + i) = o;
}

// ---------------- convert weights f32 [K][N] -> bf16 transposed [N][K] ----------------
__global__ void k_cvt_wT(const float* __restrict__ wq, const float* __restrict__ wk,
                         const float* __restrict__ wv, const float* __restrict__ wo,
                         short* __restrict__ dst) {
  __shared__ float tile[64][65];
  const float* W = (blockIdx.z == 0) ? wq : (blockIdx.z == 1) ? wk :
                   (blockIdx.z == 2) ? wv : wo;
  short* d = dst + (size_t)blockIdx.z * (D_*D_);
  int k0 = blockIdx.x * 64, n0 = blockIdx.y * 64;
  int t = threadIdx.x;
  for (int i = 0; i < 16; ++i) {
    int e = i*256 + t, r = e >> 6, c = e & 63;
    tile[r][c] = W[(size_t)(k0+r)*D_ + n0 + c];
  }
  __syncthreads();
  for (int i = 0; i < 16; ++i) {
    int e = i*256 + t, r = e >> 6, c = e & 63;
    d[(size_t)(n0+r)*D_ + k0 + c] = f2b(tile[c][r]);
  }
}

// ---------------- convert res-layer weights to bf16 (transposed) ----------------
__global__ void k_cvt_rl(const float* __restrict__ w1, const float* __restrict__ w2,
                         short* __restrict__ w1T, short* __restrict__ w2T) {
  __shared__ float tile[64][65];
  int z = blockIdx.z, l = z >> 1, which = z & 1;
  int bx = blockIdx.x, t = threadIdx.x;
  if (which == 0) {
    const float* src = w1 + (size_t)l*65536;
    short* d = w1T + (size_t)l*65536;
    int n0 = bx*64;
    for (int i = 0; i < 16; ++i) {
      int e = i*256 + t, r = e >> 6, c = e & 63;
      tile[r][c] = src[(size_t)r*1024 + n0 + c];
    }
    __syncthreads();
    for (int i = 0; i < 16; ++i) {
      int e = i*256 + t, r = e >> 6, c = e & 63;
      d[(size_t)(n0+r)*64 + c] = f2b(tile[c][r]);
    }
  } else {
    const float* src = w2 + (size_t)l*65536;
    short* d = w2T + (size_t)l*65536;
    int k0 = bx*64;
    for (int i = 0; i < 16; ++i) {
      int e = i*256 + t, r = e >> 6, c = e & 63;
      tile[r][c] = src[(size_t)(k0+r)*64 + c];
    }
    __syncthreads();
    for (int i = 0; i < 16; ++i) {
      int e = i*256 + t, r = e >> 6, c = e & 63;
      d[(size_t)r*1024 + k0 + c] = f2b(tile[c][r]);
    }
  }
}

// ---------------- 128x128 bf16 GEMM: C = X @ WT^T + bias ----------------
__global__ __launch_bounds__(256) void k_gemm(
    const short* __restrict__ Xall, const short* __restrict__ WTall,
    const float* __restrict__ b0, const float* __restrict__ b1v,
    const float* __restrict__ b2v, short* __restrict__ dstall,
    float* __restrict__ outf, int mode) {
  __shared__ short As[128*72];
  __shared__ short Bs[128*72];
  int z = blockIdx.z;
  const short* X  = Xall + (size_t)z * (S_*D_);
  const short* WT = WTall + (size_t)z * (D_*D_);
  int m0 = blockIdx.x * 128, n0 = blockIdx.y * 128;
  int t = threadIdx.x, lane = t & 63;
  int wr = t >> 7, wc = (t >> 6) & 1;
  int rA = lane & 15, kg = lane >> 4;
  f32x4 acc[4][4] = {};
  for (int kt = 0; kt < 16; ++kt) {
#pragma unroll
    for (int i = 0; i < 4; ++i) {
      int cid = i*256 + t, row = cid >> 3, c = cid & 7;
      *(int4*)&As[row*72 + c*8] = *(const int4*)&X[(size_t)(m0+row)*D_ + kt*64 + c*8];
      *(int4*)&Bs[row*72 + c*8] = *(const int4*)&WT[(size_t)(n0+row)*D_ + kt*64 + c*8];
    }
    __syncthreads();
#pragma unroll
    for (int kk = 0; kk < 2; ++kk) {
      bf16x8 a[4], b[4];
#pragma unroll
      for (int m = 0; m < 4; ++m)
        a[m] = *(const bf16x8*)&As[(wr*64 + m*16 + rA)*72 + kk*32 + kg*8];
#pragma unroll
      for (int n = 0; n < 4; ++n)
        b[n] = *(const bf16x8*)&Bs[(wc*64 + n*16 + rA)*72 + kk*32 + kg*8];
#pragma unroll
      for (int m = 0; m < 4; ++m)
#pragma unroll
        for (int n = 0; n < 4; ++n)
          acc[m][n] = MFMA16(a[m], b[n], acc[m][n]);
    }
    __syncthreads();
  }
  const float* bias = (mode == 1) ? b0 : (z == 0 ? b0 : (z == 1 ? b1v : b2v));
#pragma unroll
  for (int m = 0; m < 4; ++m) {
#pragma unroll
    for (int n = 0; n < 4; ++n) {
      int col = n0 + wc*64 + n*16 + rA;
      float bb = bias[col];
#pragma unroll
      for (int rr = 0; rr < 4; ++rr) {
        int row = m0 + wr*64 + m*16 + kg*4 + rr;
        float val = acc[m][n][rr] + bb;
        if (mode == 0) {
          int head = col >> 6, dd = col & 63;
          dstall[(size_t)z*(S_*D_) + ((size_t)head*S_ + row)*DEP_ + dd] = f2b(val);
        } else {
          outf[(size_t)row*D_ + col] = val;
        }
      }
    }
  }
}

// ---------------- bf16 transpose [h][S][64] -> [h][64][S] ----------------
__global__ void k_transpose(const short* __restrict__ qh, const short* __restrict__ vh,
                            short* __restrict__ qhT, short* __restrict__ vhT) {
  __shared__ short tile[64][68];
  const short* src = blockIdx.z ? vh : qh;
  short* dst = blockIdx.z ? vhT : qhT;
  int h = blockIdx.y, s0 = blockIdx.x * 64, t = threadIdx.x;
  for (int i = 0; i < 16; ++i) {
    int e = i*256 + t, r = e >> 6, c = e & 63;
    tile[r][c] = src[((size_t)h*S_ + s0 + r)*DEP_ + c];
  }
  __syncthreads();
  for (int i = 0; i < 16; ++i) {
    int e = i*256 + t, r = e >> 6, c = e & 63;
    dst[((size_t)h*DEP_ + r)*S_ + s0 + c] = tile[c][r];
  }
}

// ---------------- metric partial: Apart[kc][h] = qh^T qh over K-chunk ----------------
__global__ __launch_bounds__(256) void k_metric_p(const short* __restrict__ qhT,
                                                  float* __restrict__ Apart) {
  __shared__ short qt[64*72];
  int kc = blockIdx.x, h = blockIdx.y, t = threadIdx.x, lane = t & 63;
  int wr = t >> 7, wc = (t >> 6) & 1;
  int rA = lane & 15, kg = lane >> 4;
  f32x4 acc[2][2] = {};
  for (int kt = 0; kt < 4; ++kt) {
#pragma unroll
    for (int i = 0; i < 2; ++i) {
      int cid = i*256 + t, row = cid >> 3, c = cid & 7;
      *(int4*)&qt[row*72 + c*8] =
        *(const int4*)&qhT[((size_t)h*DEP_ + row)*S_ + kc*256 + kt*64 + c*8];
    }
    __syncthreads();
#pragma unroll
    for (int kk = 0; kk < 2; ++kk) {
      bf16x8 a[2], b[2];
#pragma unroll
      for (int m = 0; m < 2; ++m)
        a[m] = *(const bf16x8*)&qt[(wr*32 + m*16 + rA)*72 + kk*32 + kg*8];
#pragma unroll
      for (int n = 0; n < 2; ++n)
        b[n] = *(const bf16x8*)&qt[(wc*32 + n*16 + rA)*72 + kk*32 + kg*8];
#pragma unroll
      for (int m = 0; m < 2; ++m)
#pragma unroll
        for (int n = 0; n < 2; ++n)
          acc[m][n] = MFMA16(a[m], b[n], acc[m][n]);
    }
    __syncthreads();
  }
#pragma unroll
  for (int m = 0; m < 2; ++m)
#pragma unroll
    for (int n = 0; n < 2; ++n)
#pragma unroll
      for (int rr = 0; rr < 4; ++rr) {
        int row = wr*32 + m*16 + kg*4 + rr, col = wc*32 + n*16 + rA;
        Apart[((size_t)(kc*16 + h))*4096 + row*64 + col] = acc[m][n][rr];
      }
}

// ---------------- metric reduce: A0f (f32) + Afb (bf16) ----------------
__global__ void k_metric_r(const float* __restrict__ Apart, float* __restrict__ A0f,
                           short* __restrict__ Afb) {
  int h = blockIdx.x, t = threadIdx.x;
#pragma unroll
  for (int i = 0; i < 4; ++i) {
    int idx = i*1024 + t*4;
    f32x4 s = {};
#pragma unroll
    for (int kc = 0; kc < 8; ++kc)
      s += *(const f32x4*)&Apart[((size_t)(kc*16 + h))*4096 + idx];
    *(f32x4*)&A0f[(size_t)h*4096 + idx] = s;
    union { int2 v; short sh[4]; } pk;
#pragma unroll
    for (int j = 0; j < 4; ++j) pk.sh[j] = f2b(s[j]);
    *(int2*)&Afb[(size_t)h*4096 + idx] = pk.v;
  }
}

// ---------------- d1: hd = relu(Af @ w1 + b1) ----------------
__global__ __launch_bounds__(256) void k_d1(const short* __restrict__ Afb,
                                            const short* __restrict__ w1Tl,
                                            const float* __restrict__ b1l,
                                            short* __restrict__ hd) {
  __shared__ short As[64*72];
  __shared__ short Bs[128*72];
  int bcol = blockIdx.x * 128, h = blockIdx.y;
  int t = threadIdx.x, lane = t & 63, w = t >> 6;
  int rA = lane & 15, kg = lane >> 4;
#pragma unroll
  for (int i = 0; i < 2; ++i) {
    int cid = i*256 + t, row = cid >> 3, c = cid & 7;
    *(int4*)&As[row*72 + c*8] = *(const int4*)&Afb[(size_t)h*4096 + row*64 + c*8];
  }
#pragma unroll
  for (int i = 0; i < 4; ++i) {
    int cid = i*256 + t, row = cid >> 3, c = cid & 7;
    *(int4*)&Bs[row*72 + c*8] = *(const int4*)&w1Tl[(size_t)(bcol+row)*64 + c*8];
  }
  __syncthreads();
  f32x4 acc[2][4] = {};
#pragma unroll
  for (int kk = 0; kk < 2; ++kk) {
    bf16x8 aA[4], bW[2];
#pragma unroll
    for (int mf = 0; mf < 4; ++mf)
      aA[mf] = *(const bf16x8*)&As[(mf*16 + rA)*72 + kk*32 + kg*8];
#pragma unroll
    for (int nf = 0; nf < 2; ++nf)
      bW[nf] = *(const bf16x8*)&Bs[(w*32 + nf*16 + rA)*72 + kk*32 + kg*8];
#pragma unroll
    for (int nf = 0; nf < 2; ++nf)
#pragma unroll
      for (int mf = 0; mf < 4; ++mf)
        acc[nf][mf] = MFMA16(bW[nf], aA[mf], acc[nf][mf]);   // swapped: D[c][r]
  }
#pragma unroll
  for (int nf = 0; nf < 2; ++nf) {
    int cb = bcol + w*32 + nf*16 + kg*4;
    f32x4 b1v = *(const f32x4*)&b1l[cb];
#pragma unroll
    for (int mf = 0; mf < 4; ++mf) {
      int r = mf*16 + rA;
      union { int2 v; short s[4]; } pk;
#pragma unroll
      for (int rr = 0; rr < 4; ++rr)
        pk.s[rr] = f2b(fmaxf(acc[nf][mf][rr] + b1v[rr], 0.f));
      *(int2*)&hd[((size_t)h*64 + r)*1024 + cb] = pk.v;
    }
  }
}

// ---------------- d2 partial over K-chunks ----------------
__global__ __launch_bounds__(256) void k_d2p(const short* __restrict__ hd,
                                             const short* __restrict__ w2Tl,
                                             float* __restrict__ d2part) {
  __shared__ short hs[64*72];
  __shared__ short ws2[64*72];
  int kc = blockIdx.x, h = blockIdx.y, t = threadIdx.x, lane = t & 63;
  int wr = t >> 7, wc = (t >> 6) & 1;
  int rA = lane & 15, kg = lane >> 4;
  f32x4 acc[2][2] = {};
  for (int kt = 0; kt < 4; ++kt) {
#pragma unroll
    for (int i = 0; i < 2; ++i) {
      int cid = i*256 + t, row = cid >> 3, c = cid & 7;
      *(int4*)&hs[row*72 + c*8]  =
        *(const int4*)&hd[((size_t)h*64 + row)*1024 + kc*256 + kt*64 + c*8];
      *(int4*)&ws2[row*72 + c*8] =
        *(const int4*)&w2Tl[(size_t)row*1024 + kc*256 + kt*64 + c*8];
    }
    __syncthreads();
#pragma unroll
    for (int kk = 0; kk < 2; ++kk) {
      bf16x8 a[2], b[2];
#pragma unroll
      for (int m = 0; m < 2; ++m)
        a[m] = *(const bf16x8*)&hs[(wr*32 + m*16 + rA)*72 + kk*32 + kg*8];
#pragma unroll
      for (int n = 0; n < 2; ++n)
        b[n] = *(const bf16x8*)&ws2[(wc*32 + n*16 + rA)*72 + kk*32 + kg*8];
#pragma unroll
      for (int m = 0; m < 2; ++m)
#pragma unroll
        for (int n = 0; n < 2; ++n)
          acc[m][n] = MFMA16(a[m], b[n], acc[m][n]);
    }
    __syncthreads();
  }
#pragma unroll
  for (int m = 0; m < 2; ++m)
#pragma unroll
    for (int n = 0; n < 2; ++n)
#pragma unroll
      for (int rr = 0; rr < 4; ++rr) {
        int row = wr*32 + m*16 + kg*4 + rr, col = wc*32 + n*16 + rA;
        d2part[((size_t)(kc*16 + h))*4096 + row*64 + col] = acc[m][n][rr];
      }
}

// ---------------- d2 reduce + residual + LN (+ avAp on layer 1) ----------------
__global__ __launch_bounds__(256) void k_d2r_ln(
    const float* __restrict__ d2part, const float* __restrict__ b2l,
    const float* __restrict__ AresIn, const float* __restrict__ gl,
    const float* __restrict__ bel, short* __restrict__ Afb,
    float* __restrict__ AresOut, float* __restrict__ outB,
    const float* __restrict__ pwv, const float* __restrict__ av,
    const float* __restrict__ bav, float* __restrict__ avApW, int layer) {
  __shared__ float Xf[64][68];
  __shared__ float red[4][64];
  int h = blockIdx.x, t = threadIdx.x;
  int r = t >> 2, q4 = t & 3;
  float xv[16], s1 = 0.f, s2 = 0.f;
#pragma unroll
  for (int jj = 0; jj < 4; ++jj) {
    f32x4 s = {};
#pragma unroll
    for (int kc = 0; kc < 4; ++kc)
      s += *(const f32x4*)&d2part[((size_t)(kc*16 + h))*4096 + r*64 + q4*16 + jj*4];
#pragma unroll
    for (int j = 0; j < 4; ++j) {
      int c = q4*16 + jj*4 + j;
      float x = s[j] + b2l[c] + AresIn[(size_t)h*4096 + r*64 + c];
      xv[jj*4 + j] = x;
      s1 += x; s2 += x*x;
    }
  }
  s1 += __shfl_xor(s1, 1); s1 += __shfl_xor(s1, 2);
  s2 += __shfl_xor(s2, 1); s2 += __shfl_xor(s2, 2);
  float mean = s1 * (1.f/64.f);
  float var  = s2 * (1.f/64.f) - mean*mean;
  float rstd = rsqrtf(var + 1e-6f);
#pragma unroll
  for (int j = 0; j < 16; ++j) {
    int c = q4*16 + j;
    float nx = (xv[j] - mean)*rstd*gl[c] + bel[c];
    Afb[(size_t)h*4096 + r*64 + c] = f2b(nx);
    if (layer == 0) AresOut[(size_t)h*4096 + r*64 + c] = nx;
    else            outB[OFF_A + (size_t)h*4096 + r*64 + c] = nx;
    Xf[r][c] = nx;
  }
  if (layer == 1) {
    __syncthreads();
    int e = t & 63, dg = t >> 6;
    float pe = pwv[e], p = 0.f;
    for (int j = 0; j < 16; ++j) {
      int d = dg*16 + j;
      p += av[d] * powf(fabsf(Xf[d][e]) + 1e-9f, pe);
    }
    red[dg][e] = p;
    __syncthreads();
    if (t < 64) {
      float tot = red[0][t] + red[1][t] + red[2][t] + red[3][t];
      avApW[h*64 + t] = tot;
      outB[OFF_AVAP + h*64 + t] = tot;
    }
    if (h == 0) {
      if (t < 64) outB[OFF_PW + t] = pwv[t];
      if (t == 0) outB[OFF_BA] = bav[0];
    }
  }
}

// ---------------- pass1: E, Ep (float4 nt stores), softmax partials ----------------
__global__ __launch_bounds__(256) void k_pass1(
    const short* __restrict__ qh, const short* __restrict__ kh,
    const float* __restrict__ avAp, const float* __restrict__ mask,
    const float* __restrict__ bap, float* __restrict__ outB,
    float2* __restrict__ part) {
  __shared__ short Qs[128*64];
  __shared__ short Ks[128*64];
  __shared__ float avl[64];
  int tt = blockIdx.x, st = blockIdx.y, h = blockIdx.z;
  int s0 = st*128, t0 = tt*128;
  int t = threadIdx.x, lane = t & 63;
  int wr = t >> 7, wc = (t >> 6) & 1;
  int rA = lane & 15, kg = lane >> 4;
  if (t < 16) *(f32x4*)&avl[t*4] = *(const f32x4*)&avAp[h*64 + t*4];
  __syncthreads();
#pragma unroll
  for (int i = 0; i < 4; ++i) {
    int cid = i*256 + t, row = cid >> 3, c = cid & 7, cs = c ^ (row & 7);
    union { int4 v; short s[8]; } qa, qo;
    qa.v = *(const int4*)&qh[((size_t)h*S_ + s0 + row)*DEP_ + c*8];
#pragma unroll
    for (int j = 0; j < 8; ++j) qo.s[j] = f2b(b2f(qa.s[j]) * avl[c*8 + j]);
    *(int4*)&Qs[row*64 + cs*8] = qo.v;
    *(int4*)&Ks[row*64 + cs*8] = *(const int4*)&kh[((size_t)h*S_ + t0 + row)*DEP_ + c*8];
  }
  __syncthreads();
  f32x4 acc[4][4] = {};
#pragma unroll
  for (int kk = 0; kk < 2; ++kk) {
    bf16x8 a[4], b[4];
#pragma unroll
    for (int m = 0; m < 4; ++m) {
      int row = wr*64 + m*16 + rA, c = (kk*4 + kg) ^ (row & 7);
      a[m] = *(const bf16x8*)&Qs[row*64 + c*8];
    }
#pragma unroll
    for (int n = 0; n < 4; ++n) {
      int row = wc*64 + n*16 + rA, c = (kk*4 + kg) ^ (row & 7);
      b[n] = *(const bf16x8*)&Ks[row*64 + c*8];
    }
#pragma unroll
    for (int m = 0; m < 4; ++m)
#pragma unroll
      for (int n = 0; n < 4; ++n)
        acc[m][n] = MFMA16(b[n], a[m], acc[m][n]);   // swapped: lane holds 4 consecutive t
  }
  float bav = bap[0];
  f32x4 mk[4];
#pragma unroll
  for (int n = 0; n < 4; ++n) {
    f32x4 mm = *(const f32x4*)&mask[t0 + wc*64 + n*16 + kg*4];
#pragma unroll
    for (int j = 0; j < 4; ++j) mk[n][j] = mm[j] * (-1e9f);
  }
  float* Eo  = outB + OFF_E;
  float* Epo = outB + OFF_EP;
#pragma unroll
  for (int m = 0; m < 4; ++m) {
    int row = s0 + wr*64 + m*16 + rA;
    size_t rb = ((size_t)h*S_ + row)*S_ + t0 + wc*64;
    float mx = -3.4e38f;
    f32x4 ep4[4];
#pragma unroll
    for (int n = 0; n < 4; ++n) {
      f32x4 e = acc[m][n];
      st_nt(&Eo[rb + n*16 + kg*4], e);
      f32x4 ep;
#pragma unroll
      for (int j = 0; j < 4; ++j) {
        float ee = e[j];
        ep[j] = (ee > 0.f ? ee : 0.2f*ee) + bav + mk[n][j];
        mx = fmaxf(mx, ep[j]);
      }
      ep4[n] = ep;
      st_nt(&Epo[rb + n*16 + kg*4], ep);
    }
    mx = fmaxf(mx, __shfl_xor(mx, 16));
    mx = fmaxf(mx, __shfl_xor(mx, 32));
    float sm = 0.f;
#pragma unroll
    for (int n = 0; n < 4; ++n)
#pragma unroll
      for (int j = 0; j < 4; ++j) sm += expf(ep4[n][j] - mx);
    sm += __shfl_xor(sm, 16);
    sm += __shfl_xor(sm, 32);
    if (kg == 0)
      part[((size_t)(h*S_ + row)*16 + tt)*2 + wc] = make_float2(mx, sm);
  }
}

// ---------------- softmax stats reduce ----------------
__global__ void k_sreduce(const float2* __restrict__ part, float2* __restrict__ fin) {
  int row = blockIdx.x * 256 + threadIdx.x;
  const float2* pp = part + (size_t)row * 32;
  float M = -3.4e38f;
  float2 p[32];
#pragma unroll
  for (int i = 0; i < 32; ++i) { p[i] = pp[i]; M = fmaxf(M, p[i].x); }
  float L = 0.f;
#pragma unroll
  for (int i = 0; i < 32; ++i) L += p[i].y * expf(p[i].x - M);
  fin[row] = make_float2(M, L);
}

// ---------------- pass2: attv (float4 nt) + PV partial ----------------
__global__ __launch_bounds__(256) void k_pass2(
    const short* __restrict__ qh, const short* __restrict__ kh,
    const short* __restrict__ vhT, const float* __restrict__ avAp,
    const float* __restrict__ mask, const float* __restrict__ bap,
    const float2* __restrict__ fin, float* __restrict__ attv,
    short* __restrict__ Hnp) {
  __shared__ short Qs[128*64];
  __shared__ short KP[128*128];   // union: kh tile (stride 64) / P tile (stride 128, swz)
  __shared__ short Vs[64*128];
  __shared__ float avl[64];
  int st = blockIdx.x, tc = blockIdx.y, h = blockIdx.z;
  int s0 = st * 128;
  int t = threadIdx.x, lane = t & 63;
  int wr = t >> 7, wc = (t >> 6) & 1;
  int rA = lane & 15, kg = lane >> 4;
  if (t < 16) *(f32x4*)&avl[t*4] = *(const f32x4*)&avAp[h*64 + t*4];
  __syncthreads();
#pragma unroll
  for (int i = 0; i < 4; ++i) {
    int cid = i*256 + t, row = cid >> 3, c = cid & 7, cs = c ^ (row & 7);
    union { int4 v; short s[8]; } qa, qo;
    qa.v = *(const int4*)&qh[((size_t)h*S_ + s0 + row)*DEP_ + c*8];
#pragma unroll
    for (int j = 0; j < 8; ++j) qo.s[j] = f2b(b2f(qa.s[j]) * avl[c*8 + j]);
    *(int4*)&Qs[row*64 + cs*8] = qo.v;
  }
  float Ms[4], Li[4];
#pragma unroll
  for (int m = 0; m < 4; ++m) {
    float2 f = fin[h*S_ + s0 + wr*64 + m*16 + rA];
    Ms[m] = f.x; Li[m] = 1.f / f.y;
  }
  float bav = bap[0];
  __syncthreads();
  bf16x8 aq[4][2];
#pragma unroll
  for (int m = 0; m < 4; ++m)
#pragma unroll
    for (int kk = 0; kk < 2; ++kk) {
      int row = wr*64 + m*16 + rA, c = (kk*4 + kg) ^ (row & 7);
      aq[m][kk] = *(const bf16x8*)&Qs[row*64 + c*8];
    }
  f32x4 acc2[4][2] = {};
  for (int tt = tc*8; tt < tc*8 + 8; ++tt) {
    int t0 = tt * 128;
    __syncthreads();    // prev iteration's P/V reads done
#pragma unroll
    for (int i = 0; i < 4; ++i) {
      int cid = i*256 + t, row = cid >> 3, c = cid & 7, cs = c ^ (row & 7);
      *(int4*)&KP[row*64 + cs*8] = *(const int4*)&kh[((size_t)h*S_ + t0 + row)*DEP_ + c*8];
    }
#pragma unroll
    for (int i = 0; i < 4; ++i) {
      int cid = i*256 + t, row = cid >> 4, c = cid & 15, cs = c ^ (row & 7);
      *(int4*)&Vs[row*128 + cs*8] = *(const int4*)&vhT[((size_t)h*DEP_ + row)*S_ + t0 + c*8];
    }
    __syncthreads();
    f32x4 accE[4][4] = {};
#pragma unroll
    for (int kk = 0; kk < 2; ++kk) {
      bf16x8 b[4];
#pragma unroll
      for (int n = 0; n < 4; ++n) {
        int row = wc*64 + n*16 + rA, c = (kk*4 + kg) ^ (row & 7);
        b[n] = *(const bf16x8*)&KP[row*64 + c*8];
      }
#pragma unroll
      for (int m = 0; m < 4; ++m)
#pragma unroll
        for (int n = 0; n < 4; ++n)
          accE[m][n] = MFMA16(b[n], aq[m][kk], accE[m][n]);   // swapped
    }
    f32x4 mk[4];
#pragma unroll
    for (int n = 0; n < 4; ++n) {
      f32x4 mm = *(const f32x4*)&mask[t0 + wc*64 + n*16 + kg*4];
#pragma unroll
      for (int j = 0; j < 4; ++j) mk[n][j] = mm[j] * (-1e9f);
    }
#pragma unroll
    for (int m = 0; m < 4; ++m) {
      size_t rb = ((size_t)h*S_ + s0 + wr*64 + m*16 + rA)*S_ + t0 + wc*64;
#pragma unroll
      for (int n = 0; n < 4; ++n) {
        f32x4 e = accE[m][n], p;
#pragma unroll
        for (int j = 0; j < 4; ++j) {
          float ep = (e[j] > 0.f ? e[j] : 0.2f*e[j]) + bav + mk[n][j];
          p[j] = expf(ep - Ms[m]) * Li[m];
        }
        st_nt(&attv[rb + n*16 + kg*4], p);
        accE[m][n] = p;
      }
    }
    __syncthreads();    // all KP(kh) fragment reads done before P overwrites
#pragma unroll
    for (int m = 0; m < 4; ++m) {
      int srow = wr*64 + m*16 + rA;
#pragma unroll
      for (int n = 0; n < 4; ++n) {
        int tcol = wc*64 + n*16 + kg*4;
        union { int2 v; short s[4]; } pk;
#pragma unroll
        for (int j = 0; j < 4; ++j) pk.s[j] = f2b(accE[m][n][j]);
        *(int2*)((char*)KP + srow*256 + ((tcol*2) ^ ((srow & 7) << 4))) = pk.v;
      }
    }
    __syncthreads();
#pragma unroll
    for (int kkp = 0; kkp < 4; ++kkp) {
      bf16x8 ap[4], bv[2];
#pragma unroll
      for (int m = 0; m < 4; ++m) {
        int row = wr*64 + m*16 + rA;
        ap[m] = *(const bf16x8*)((const char*)KP + row*256 + ((kkp*64 + kg*16) ^ ((row & 7) << 4)));
      }
#pragma unroll
      for (int n = 0; n < 2; ++n) {
        int dd = wc*32 + n*16 + rA, c = (kkp*4 + kg) ^ (dd & 7);
        bv[n] = *(const bf16x8*)&Vs[dd*128 + c*8];
      }
#pragma unroll
      for (int m = 0; m < 4; ++m)
#pragma unroll
        for (int n = 0; n < 2; ++n)
          acc2[m][n] = MFMA16(ap[m], bv[n], acc2[m][n]);
    }
  }
  short* Hp = Hnp + (size_t)tc * (S_*D_);
#pragma unroll
  for (int m = 0; m < 4; ++m)
#pragma unroll
    for (int n = 0; n < 2; ++n)
#pragma unroll
      for (int rr = 0; rr < 4; ++rr) {
        int row = s0 + wr*64 + m*16 + kg*4 + rr;
        int dd = wc*32 + n*16 + rA;
        Hp[(size_t)row*D_ + h*DEP_ + dd] = f2b(acc2[m][n][rr]);
      }
}

// ---------------- sum the 2 PV partials -> Hn bf16 ----------------
__global__ void k_hred(const short* __restrict__ Hnp, short* __restrict__ Hn) {
  size_t i = ((size_t)blockIdx.x*256 + threadIdx.x)*8;
  union { int4 v; short s[8]; } a, b, o;
  a.v = *(const int4*)&Hnp[i];
  b.v = *(const int4*)&Hnp[(size_t)S_*D_ + i];
#pragma unroll
  for (int j = 0; j < 8; ++j) o.s[j] = f2b(b2f(a.s[j]) + b2f(b.s[j]));
  *(int4*)&Hn[i] = o.v;
}

extern "C" void kernel_launch(void* const* d_in, const int* in_sizes, int n_in,
                              void* d_out, int out_size, void* d_ws, size_t ws_size,
                              hipStream_t stream) {
  (void)in_sizes; (void)n_in; (void)out_size; (void)ws_size;
  const float* q    = (const float*)d_in[0];
  const float* k    = (const float*)d_in[1];
  const float* v    = (const float*)d_in[2];
  const float* mask = (const float*)d_in[3];
  const float* wq_w = (const float*)d_in[4];
  const float* wq_b = (const float*)d_in[5];
  const float* wk_w = (const float*)d_in[6];
  const float* wk_b = (const float*)d_in[7];
  const float* wv_w = (const float*)d_in[8];
  const float* wv_b = (const float*)d_in[9];
  const float* wo_w = (const float*)d_in[10];
  const float* wo_b = (const float*)d_in[11];
  const float* rl_w1 = (const float*)d_in[12];
  const float* rl_b1 = (const float*)d_in[13];
  const float* rl_w2 = (const float*)d_in[14];
  const float* rl_b2 = (const float*)d_in[15];
  const float* rl_g  = (const float*)d_in[16];
  const float* rl_be = (const float*)d_in[17];
  const float* pw    = (const float*)d_in[18];
  const float* avec  = (const float*)d_in[19];
  const float* ba    = (const float*)d_in[20];
  float* outf = (float*)d_out;

  // Workspace map (lifetime-based reuse, peak <= 32.5 MB)
  char* w = (char*)d_ws;
  short* xbf  = (short*)(w);                              // 0..12M (dead after QKV gemm)
  short* wT   = (short*)(w + (12u << 20));                // 12..20M; wq/wk/wvT dead after QKV
  short* qh   = (short*)(w + (20u << 20));                // 20..24M (live to pass2)
  short* kh   = (short*)(w + (24u << 20));                // 24..28M (live to pass2)
  short* vh   = (short*)(w + (28u << 20));                // 28..32M (dead after transpose)
  short* qhT  = (short*)(w);                              // 0..4M  (over xbf-q; dead after metric_p)
  short* vhT  = (short*)(w + (4u << 20));                 // 4..8M  (live to pass2)
  short* hd   = (short*)(w + (8u << 20));                 // 8..10M (dead after d2p l1)
  short* w1T  = (short*)(w + (10u << 20));                // 256KB
  short* w2T  = (short*)(w + (10u << 20) + (256u << 10)); // 256KB
  short* Afbf = (short*)(w + (10u << 20) + (512u << 10)); // 128KB
  float* Ares0 = (float*)(w + (11u << 20));               // 256KB
  float* Ares1 = (float*)(w + (11u << 20) + (256u << 10));// 256KB
  float* Apart = (float*)(w + (12u << 20));               // 2MB over wqT (dead)
  float* d2part = (float*)(w + (14u << 20));              // 1MB over wkT (dead)
  float2* part = (float2*)(w + (8u << 20));               // 8..16M during pass1 (res bufs dead)
  float2* fin  = (float2*)(w + (16u << 20));              // 256KB over wvT (dead)
  float* avApW = (float*)(w + (16u << 20) + (512u << 10));// 4KB
  short* Hnp  = (short*)(w + (8u << 20));                 // 8..16M during pass2 (part dead)
  short* Hn   = (short*)(w + (28u << 20));                // over vh (dead)

  k_cvt_in<<<dim3(2048, 1, 3), 256, 0, stream>>>(q, k, v, xbf);
  k_cvt_wT<<<dim3(16, 16, 4), 256, 0, stream>>>(wq_w, wk_w, wv_w, wo_w, wT);
  k_cvt_rl<<<dim3(16, 1, 4), 256, 0, stream>>>(rl_w1, rl_w2, w1T, w2T);
  k_gemm<<<dim3(16, 8, 3), 256, 0, stream>>>(xbf, wT, wq_b, wk_b, wv_b, qh, nullptr, 0);
  k_transpose<<<dim3(32, 16, 2), 256, 0, stream>>>(qh, vh, qhT, vhT);
  k_metric_p<<<dim3(8, 16), 256, 0, stream>>>(qhT, Apart);
  k_metric_r<<<dim3(16), 256, 0, stream>>>(Apart, Ares0, Afbf);
  // res layer 0
  k_d1<<<dim3(8, 16), 256, 0, stream>>>(Afbf, w1T, rl_b1, hd);
  k_d2p<<<dim3(4, 16), 256, 0, stream>>>(hd, w2T, d2part);
  k_d2r_ln<<<dim3(16), 256, 0, stream>>>(d2part, rl_b2, Ares0, rl_g, rl_be,
                                         Afbf, Ares1, outf, pw, avec, ba, avApW, 0);
  // res layer 1
  k_d1<<<dim3(8, 16), 256, 0, stream>>>(Afbf, w1T + 65536, rl_b1 + 1024, hd);
  k_d2p<<<dim3(4, 16), 256, 0, stream>>>(hd, w2T + 65536, d2part);
  k_d2r_ln<<<dim3(16), 256, 0, stream>>>(d2part, rl_b2 + 64, Ares1, rl_g + 64, rl_be + 64,
                                         Afbf, Ares1, outf, pw, avec, ba, avApW, 1);
  k_pass1<<<dim3(16, 16, 16), 256, 0, stream>>>(qh, kh, avApW, mask, ba, outf, part);
  k_sreduce<<<dim3(128), 256, 0, stream>>>(part, fin);
  k_pass2<<<dim3(16, 2, 16), 256, 0, stream>>>(qh, kh, vhT, avApW, mask, ba, fin,
                                               outf + OFF_ATT, Hnp);
  k_hred<<<dim3(1024), 256, 0, stream>>>(Hnp, Hn);
  k_gemm<<<dim3(16, 8, 1), 256, 0, stream>>>(Hn, wT + 3u*D_*D_, wo_b, wo_b, wo_b,
                                             nullptr, outf, 1);
}